// Round 9
// baseline (1278.836 us; speedup 1.0000x reference)
//
#include <hip/hip_runtime.h>
#include <math.h>

typedef __attribute__((ext_vector_type(8))) short short8;
typedef __attribute__((ext_vector_type(4))) short short4v;
typedef __attribute__((ext_vector_type(4))) float f32x4;

__device__ __forceinline__ unsigned short f2b(float f) {
  unsigned u = __float_as_uint(f);
  return (unsigned short)((u + 0x7fffu + ((u >> 16) & 1u)) >> 16);
}
__device__ __forceinline__ float b2f(unsigned short h) {
  return __uint_as_float(((unsigned)h) << 16);
}
__device__ __forceinline__ f32x4 mfma16(short8 a, short8 b, f32x4 c) {
  return __builtin_amdgcn_mfma_f32_16x16x32_bf16(a, b, c, 0, 0, 0);
}
template <int STRIDE>
__device__ __forceinline__ short8 lds8(const short* buf, int row, int k) {
  int idx = (row * STRIDE + k) ^ ((row & 7) << 3);
  return *(const short8*)(buf + idx);
}
template <int STRIDE>
__device__ __forceinline__ void ldsw(short* buf, int row, int col, unsigned short v) {
  buf[(row * STRIDE + col) ^ ((row & 7) << 3)] = (short)v;
}
__device__ __forceinline__ float red16sum(float v) {
  v += __shfl_xor(v, 1); v += __shfl_xor(v, 2);
  v += __shfl_xor(v, 4); v += __shfl_xor(v, 8);
  return v;
}
__device__ __forceinline__ float red16max(float v) {
  v = fmaxf(v, __shfl_xor(v, 1)); v = fmaxf(v, __shfl_xor(v, 2));
  v = fmaxf(v, __shfl_xor(v, 4)); v = fmaxf(v, __shfl_xor(v, 8));
  return v;
}
__device__ __forceinline__ void gll16(const short* src, short* lds) {
  __builtin_amdgcn_global_load_lds(
      (const __attribute__((address_space(1))) unsigned int*)src,
      (__attribute__((address_space(3))) unsigned int*)lds, 16, 0, 0);
}
// combine NS split stats -> mean, rstd (row length 256)
template <int NS>
__device__ __forceinline__ void rowstat(const float* st, int row, float& mu, float& rho) {
  float s1 = 0.f, s2 = 0.f;
#pragma unroll
  for (int i = 0; i < NS; ++i) {
    s1 += st[(row * NS + i) * 2];
    s2 += st[(row * NS + i) * 2 + 1];
  }
  mu = s1 * (1.f / 256.f);
  rho = rsqrtf(s2 * (1.f / 256.f) - mu * mu + 1e-12f);
}
// B-fragment addr inside a swizzled chunk (n local, chunk holds NLOC cols x 32 k)
__device__ __forceinline__ int bswz(int n, int g4) {
  return ((n * 32 + g4 * 8) ^ ((n & 7) << 3));
}

// ---- weight prep: f32 [K][N] -> pre-swizzled bf16 chunks, LN-folded where used ----
// shorts: WQ 0 | WK 131072 | WV 262144 | WO 393216 | WI 524288 | WOUT 786432 | WP 1048576
__global__ void prep_w(const float* __restrict__ qw, const float* __restrict__ kw,
                       const float* __restrict__ vw, const float* __restrict__ ow,
                       const float* __restrict__ iw, const float* __restrict__ outw,
                       const float* __restrict__ pw, const float* __restrict__ og,
                       const float* __restrict__ ag, short* __restrict__ ws) {
  int t = blockIdx.x * 256 + threadIdx.x;  // 1,114,112 total
  float val; int base, n, k;
  if (t < 524288) {
    int which = t >> 17, r = t & 131071;
    int ly = r >> 16, e = r & 65535;
    n = e >> 8; k = e & 255;
    const float* m = which == 0 ? qw : which == 1 ? kw : which == 2 ? vw : ow;
    val = m[(ly * 256 + k) * 256 + n];
    if (which < 3 && ly == 1) val *= og[k];  // fold layer-0 out_g into layer-1 qkv
    base = which * 131072 + ly * 65536;
  } else if (t < 786432) {
    int e = t - 524288;
    int ly = e >> 17, f = e & 131071, g2 = f >> 16, e2 = f & 65535;
    n = e2 >> 8; k = e2 & 255;
    val = iw[(ly * 256 + k) * 512 + g2 * 256 + n] * ag[ly * 256 + k];  // fold attn_g
    base = 524288 + ly * 131072 + g2 * 65536;
  } else if (t < 1048576) {
    int e = t - 786432;
    int ly = e >> 17, f = e & 131071;
    n = f >> 9; k = f & 511;
    val = outw[(ly * 512 + k) * 256 + n];
    base = 786432 + ly * 131072;
  } else {
    int e = t - 1048576;
    n = e >> 8; k = e & 255;
    val = pw[k * 256 + n] * og[256 + k];  // fold layer-1 out_g
    base = 1048576;
  }
  int pos = ((n * 32 + (k & 31)) ^ ((n & 7) << 3));
  ws[base + (k >> 5) * 8192 + pos] = (short)f2b(val);
}

// ---- u/v vectors for folded pairs: u[n]=sum g_c W[c][n], v[n]=sum b_c W[c][n] ----
// f32 layout in fuv: qkv [ly][y][uv][256] @0 (3072) | ffn1 [ly][uv][512] @3072 (2048)
//                    | pool [uv][256] @5120 (512)
__global__ void uv_k(const float* __restrict__ qw, const float* __restrict__ kw,
                     const float* __restrict__ vw, const float* __restrict__ iw,
                     const float* __restrict__ pw,
                     const float* __restrict__ eg, const float* __restrict__ eb,
                     const float* __restrict__ og, const float* __restrict__ ob,
                     const float* __restrict__ ag, const float* __restrict__ ab,
                     float* __restrict__ fuv) {
  int o = blockIdx.x * 256 + threadIdx.x;
  if (o >= 5632) return;
  if (o < 3072) {
    int ly = o / 1536, rem = o % 1536;
    int y = rem / 512, rem2 = rem % 512;
    int uv = rem2 / 256, n = rem2 % 256;
    const float* m = y == 0 ? qw : y == 1 ? kw : vw;
    const float* gb = (ly == 0) ? (uv ? eb : eg) : (uv ? ob : og);
    float s = 0.f;
    for (int k = 0; k < 256; ++k) s += gb[k] * m[(ly * 256 + k) * 256 + n];
    fuv[((ly * 3 + y) * 2 + uv) * 256 + n] = s;
  } else if (o < 5120) {
    int o2 = o - 3072;
    int ly = o2 / 1024, rem = o2 % 1024;
    int uv = rem / 512, n = rem % 512;
    const float* gb = uv ? (ab + ly * 256) : (ag + ly * 256);
    float s = 0.f;
    for (int k = 0; k < 256; ++k) s += gb[k] * iw[(ly * 256 + k) * 512 + n];
    fuv[3072 + (ly * 2 + uv) * 512 + n] = s;
  } else {
    int o3 = o - 5120;
    int uv = o3 / 256, n = o3 % 256;
    const float* gb = uv ? (ob + 256) : (og + 256);
    float s = 0.f;
    for (int k = 0; k < 256; ++k) s += gb[k] * pw[k * 256 + n];
    fuv[5120 + uv * 256 + n] = s;
  }
}

// ---- embedding + LN (normalized output): wave = one token ----
__global__ __launch_bounds__(256) void emb_k(
    const int* __restrict__ word, const int* __restrict__ age,
    const int* __restrict__ seg, const int* __restrict__ posi,
    const float* __restrict__ we, const float* __restrict__ se,
    const float* __restrict__ ae, const float* __restrict__ pe,
    const float* __restrict__ g, const float* __restrict__ b,
    short* __restrict__ x) {
  int w = threadIdx.x >> 6, lane = threadIdx.x & 63;
  int t = blockIdx.x * 4 + w;
  int wi = word[t], gi = seg[t], ai = age[t], pi = posi[t];
  f32x4 e = ((const f32x4*)(we + wi * 256))[lane];
  f32x4 tv = ((const f32x4*)(se + gi * 256))[lane]; e = e + tv;
  tv = ((const f32x4*)(ae + ai * 256))[lane]; e = e + tv;
  tv = ((const f32x4*)(pe + pi * 256))[lane]; e = e + tv;
  float s1 = e[0] + e[1] + e[2] + e[3];
  float s2 = e[0] * e[0] + e[1] * e[1] + e[2] * e[2] + e[3] * e[3];
#pragma unroll
  for (int m = 1; m < 64; m <<= 1) { s1 += __shfl_xor(s1, m); s2 += __shfl_xor(s2, m); }
  float mean = s1 * (1.f / 256.f);
  float rstd = rsqrtf(s2 * (1.f / 256.f) - mean * mean + 1e-12f);
  f32x4 gv = ((const f32x4*)g)[lane];
  f32x4 bv = ((const f32x4*)b)[lane];
  short4v pk;
#pragma unroll
  for (int j = 0; j < 4; ++j) pk[j] = (short)f2b((e[j] - mean) * rstd * gv[j] + bv[j]);
  *(short4v*)(x + t * 256 + lane * 4) = pk;
}

// ---- QKV: persistent half-panel, barrier-free M-loop. grid (200, 2, 3) ----
__global__ __launch_bounds__(256) void qkv_p(
    const short* __restrict__ A, const float* __restrict__ instats,  // null@ly0
    const short* __restrict__ img0,  // ws + ly*65536
    const float* __restrict__ uvb,   // fuv + ly*1536
    const float* __restrict__ qb_l, const float* __restrict__ kb_l,
    const float* __restrict__ vb_l,
    short* __restrict__ q, short* __restrict__ k2, short* __restrict__ vt) {
  __shared__ __align__(16) short panel[32768];
  __shared__ __align__(16) short rep[8192];  // 2048 shorts per wave
  int tid = threadIdx.x, w = tid >> 6, lane = tid & 63;
  int l15 = lane & 15, g4 = lane >> 4;
  int half = blockIdx.y, y = blockIdx.z;
  const short* W = img0 + y * 131072;
  const float* bias = (y == 0 ? qb_l : y == 1 ? kb_l : vb_l);
  for (int p = 0; p < 16; ++p)
    gll16(W + (p >> 1) * 8192 + half * 4096 + (p & 1) * 2048 + tid * 8,
          panel + p * 2048 + tid * 8);
  float u0[8], w0[8];
#pragma unroll
  for (int tc = 0; tc < 8; ++tc) {
    int colg = half * 128 + tc * 16 + l15;
    float uu = 0.f, vv = 0.f;
    if (instats) { uu = uvb[y * 512 + colg]; vv = uvb[y * 512 + 256 + colg]; }
    u0[tc] = uu; w0[tc] = vv + bias[colg];
  }
  __syncthreads();
  short* myrep = rep + w * 2048;
  for (int t = 0; t < 8; ++t) {
    int seq = blockIdx.x * 8 + t;
    int r0 = seq * 64;
    short8 af[8];
#pragma unroll
    for (int kk = 0; kk < 8; ++kk)
      af[kk] = *(const short8*)(A + (size_t)(r0 + w * 16 + l15) * 256 + kk * 32 + g4 * 8);
    float mu[4], rho[4];
#pragma unroll
    for (int r = 0; r < 4; ++r) {
      if (instats) rowstat<4>(instats, r0 + w * 16 + g4 * 4 + r, mu[r], rho[r]);
      else { mu[r] = 0.f; rho[r] = 1.f; }
    }
    f32x4 acc[8];
#pragma unroll
    for (int i = 0; i < 8; ++i) acc[i] = f32x4{0.f, 0.f, 0.f, 0.f};
#pragma unroll
    for (int kb = 0; kb < 8; ++kb) {
#pragma unroll
      for (int tc = 0; tc < 8; ++tc) {
        short8 bf = *(const short8*)(panel + kb * 4096 + bswz(tc * 16 + l15, g4));
        acc[tc] = mfma16(af[kb], bf, acc[tc]);
      }
    }
    if (y < 2) {
      short* out = y ? k2 : q;
#pragma unroll
      for (int tc = 0; tc < 8; ++tc)
#pragma unroll
        for (int r = 0; r < 4; ++r) {
          float val = rho[r] * (acc[tc][r] - mu[r] * u0[tc]) + w0[tc];
          myrep[(g4 * 4 + r) * 128 + tc * 16 + l15] = (short)f2b(val);
        }
#pragma unroll
      for (int i = 0; i < 4; ++i) {
        int s = i * 512 + lane * 8;
        int lr = s >> 7, lc = s & 127;
        short8 v = *(const short8*)(myrep + s);
        *(short8*)(out + (size_t)(r0 + w * 16 + lr) * 256 + half * 128 + lc) = v;
      }
    } else {  // v -> vt[seq][d][tok]
#pragma unroll
      for (int tc = 0; tc < 8; ++tc)
#pragma unroll
        for (int r = 0; r < 4; ++r) {
          float val = rho[r] * (acc[tc][r] - mu[r] * u0[tc]) + w0[tc];
          myrep[(tc * 16 + l15) * 16 + g4 * 4 + r] = (short)f2b(val);
        }
#pragma unroll
      for (int i = 0; i < 4; ++i) {
        int s = i * 512 + lane * 8;
        int d = s >> 4, tb = s & 15;
        short8 v = *(const short8*)(myrep + s);
        *(short8*)(vt + (size_t)seq * 16384 + (half * 128 + d) * 64 + w * 16 + tb) = v;
      }
    }
  }
}

// ---- attention (unchanged): block = seq, wave = head; ctx -> global ----
__global__ __launch_bounds__(256) void attn_k(
    const short* __restrict__ q, const short* __restrict__ k,
    const short* __restrict__ vt, short* __restrict__ ctx,
    const float* __restrict__ mask) {
  __shared__ __align__(16) short sAll[16384];
  int tid = threadIdx.x;
  int w = tid >> 6, lane = tid & 63;
  int l15 = lane & 15, g4 = lane >> 4;
  int n = blockIdx.x;
  const f32x4 zero4 = {0.f, 0.f, 0.f, 0.f};
  short* sPw = sAll + w * 4096;
  float amvr[4];
#pragma unroll
  for (int tc = 0; tc < 4; ++tc)
    amvr[tc] = (1.f - mask[n * 64 + tc * 16 + l15]) * -10000.f;
  const short* qn = q + (size_t)n * 16384;
  const short* kn = k + (size_t)n * 16384;
  const short* vtn = vt + (size_t)n * 16384;
  short8 qa[4][2];
#pragma unroll
  for (int st = 0; st < 4; ++st)
#pragma unroll
    for (int ks = 0; ks < 2; ++ks)
      qa[st][ks] = *(const short8*)(qn + (st * 16 + l15) * 256 + w * 64 + ks * 32 + g4 * 8);
  f32x4 sacc[4][4];
#pragma unroll
  for (int st = 0; st < 4; ++st)
#pragma unroll
    for (int tc = 0; tc < 4; ++tc) sacc[st][tc] = zero4;
#pragma unroll
  for (int ks = 0; ks < 2; ++ks)
#pragma unroll
    for (int tc = 0; tc < 4; ++tc) {
      short8 kf = *(const short8*)(kn + (tc * 16 + l15) * 256 + w * 64 + ks * 32 + g4 * 8);
#pragma unroll
      for (int st = 0; st < 4; ++st) sacc[st][tc] = mfma16(qa[st][ks], kf, sacc[st][tc]);
    }
#pragma unroll
  for (int st = 0; st < 4; ++st)
#pragma unroll
    for (int r = 0; r < 4; ++r) {
      float pv[4];
      float mx = -1e30f;
#pragma unroll
      for (int tc = 0; tc < 4; ++tc) {
        float sv = sacc[st][tc][r] * 0.125f + amvr[tc];
        pv[tc] = sv;
        mx = fmaxf(mx, sv);
      }
      mx = red16max(mx);
      float sm = 0.f;
#pragma unroll
      for (int tc = 0; tc < 4; ++tc) {
        float e = __expf(pv[tc] - mx);
        pv[tc] = e;
        sm += e;
      }
      sm = red16sum(sm);
      float inv = 1.f / sm;
#pragma unroll
      for (int tc = 0; tc < 4; ++tc)
        ldsw<64>(sPw, st * 16 + g4 * 4 + r, tc * 16 + l15, f2b(pv[tc] * inv));
    }
  __syncthreads();
  f32x4 cacc[4][4];
#pragma unroll
  for (int st = 0; st < 4; ++st)
#pragma unroll
    for (int tc = 0; tc < 4; ++tc) cacc[st][tc] = zero4;
#pragma unroll
  for (int ks = 0; ks < 2; ++ks) {
    short8 pa[4];
#pragma unroll
    for (int st = 0; st < 4; ++st) pa[st] = lds8<64>(sPw, st * 16 + l15, ks * 32 + g4 * 8);
#pragma unroll
    for (int tc = 0; tc < 4; ++tc) {
      short8 vf = *(const short8*)(vtn + (w * 64 + tc * 16 + l15) * 64 + ks * 32 + g4 * 8);
#pragma unroll
      for (int st = 0; st < 4; ++st) cacc[st][tc] = mfma16(pa[st], vf, cacc[st][tc]);
    }
  }
  __syncthreads();
#pragma unroll
  for (int st = 0; st < 4; ++st)
#pragma unroll
    for (int tc = 0; tc < 4; ++tc)
#pragma unroll
      for (int r = 0; r < 4; ++r) {
        int lrow = st * 16 + g4 * 4 + r;
        int col = w * 64 + tc * 16 + l15;
        sAll[(lrow * 256 + col) ^ ((lrow & 7) << 3)] = (short)f2b(cacc[st][tc][r]);
      }
  __syncthreads();
  short* dst = ctx + (size_t)n * 16384;
#pragma unroll
  for (int i = 0; i < 8; ++i) {
    int j = i * 256 + tid;
    int row = j >> 5, c8 = j & 31;
    short8 v = *(const short8*)(sAll + ((row * 256 + c8 * 8) ^ ((row & 7) << 3)));
    *(short8*)(dst + j * 8) = v;
  }
}

// ---- O-proj: r = ctx@wo + ob + resid; store RAW r + stats. grid (200, 2) ----
__global__ __launch_bounds__(256) void oln_p(
    const short* __restrict__ ctx, const short* __restrict__ imgW,
    const float* __restrict__ ob_l,
    const short* __restrict__ resraw, const float* __restrict__ resstats,  // null@ly0
    const float* __restrict__ gres, const float* __restrict__ bres,
    short* __restrict__ rout, float* __restrict__ statsR) {
  __shared__ __align__(16) short panel[32768];
  __shared__ __align__(16) short rep[8192];
  int tid = threadIdx.x, w = tid >> 6, lane = tid & 63;
  int l15 = lane & 15, g4 = lane >> 4;
  int half = blockIdx.y;
  for (int p = 0; p < 16; ++p)
    gll16(imgW + (p >> 1) * 8192 + half * 4096 + (p & 1) * 2048 + tid * 8,
          panel + p * 2048 + tid * 8);
  float ob0[8], gr[8], br[8];
#pragma unroll
  for (int tc = 0; tc < 8; ++tc) {
    int colg = half * 128 + tc * 16 + l15;
    ob0[tc] = ob_l[colg];
    gr[tc] = resstats ? gres[colg] : 0.f;
    br[tc] = resstats ? bres[colg] : 0.f;
  }
  __syncthreads();
  short* myrep = rep + w * 2048;
  for (int t = 0; t < 8; ++t) {
    int seq = blockIdx.x * 8 + t;
    int r0 = seq * 64;
    short8 af[8];
#pragma unroll
    for (int kk = 0; kk < 8; ++kk)
      af[kk] = *(const short8*)(ctx + (size_t)(r0 + w * 16 + l15) * 256 + kk * 32 + g4 * 8);
    f32x4 acc[8];
#pragma unroll
    for (int i = 0; i < 8; ++i) acc[i] = f32x4{0.f, 0.f, 0.f, 0.f};
#pragma unroll
    for (int kb = 0; kb < 8; ++kb) {
#pragma unroll
      for (int tc = 0; tc < 8; ++tc) {
        short8 bf = *(const short8*)(panel + kb * 4096 + bswz(tc * 16 + l15, g4));
        acc[tc] = mfma16(af[kb], bf, acc[tc]);
      }
    }
    // residual tile -> wave LDS (coalesced)
#pragma unroll
    for (int i = 0; i < 4; ++i) {
      int s = i * 512 + lane * 8;
      int lr = s >> 7, lc = s & 127;
      short8 v = *(const short8*)(resraw + (size_t)(r0 + w * 16 + lr) * 256 + half * 128 + lc);
      *(short8*)(myrep + s) = v;
    }
    float muR[4], rhoR[4];
#pragma unroll
    for (int r = 0; r < 4; ++r) {
      if (resstats) rowstat<4>(resstats, r0 + w * 16 + g4 * 4 + r, muR[r], rhoR[r]);
      else { muR[r] = 0.f; rhoR[r] = 1.f; }
    }
    float s1[4] = {0.f, 0.f, 0.f, 0.f}, s2[4] = {0.f, 0.f, 0.f, 0.f};
#pragma unroll
    for (int tc = 0; tc < 8; ++tc)
#pragma unroll
      for (int r = 0; r < 4; ++r) {
        float raw = b2f((unsigned short)myrep[(g4 * 4 + r) * 128 + tc * 16 + l15]);
        float resid = resstats ? ((raw - muR[r]) * rhoR[r] * gr[tc] + br[tc]) : raw;
        float val = acc[tc][r] + ob0[tc] + resid;
        acc[tc][r] = val;
        s1[r] += val; s2[r] += val * val;
      }
#pragma unroll
    for (int r = 0; r < 4; ++r) {
      float a = red16sum(s1[r]), qq = red16sum(s2[r]);
      if (l15 == 0) {
        int row = r0 + w * 16 + g4 * 4 + r;
        statsR[(row * 2 + half) * 2] = a;
        statsR[(row * 2 + half) * 2 + 1] = qq;
      }
    }
#pragma unroll
    for (int tc = 0; tc < 8; ++tc)
#pragma unroll
      for (int r = 0; r < 4; ++r)
        myrep[(g4 * 4 + r) * 128 + tc * 16 + l15] = (short)f2b(acc[tc][r]);
#pragma unroll
    for (int i = 0; i < 4; ++i) {
      int s = i * 512 + lane * 8;
      int lr = s >> 7, lc = s & 127;
      short8 v = *(const short8*)(myrep + s);
      *(short8*)(rout + (size_t)(r0 + w * 16 + lr) * 256 + half * 128 + lc) = v;
    }
  }
}

// ---- FFN1: h = gelu(fold(r)@wi' + ib). grid (200, 4) ----
__global__ __launch_bounds__(256) void ffn1_p(
    const short* __restrict__ rraw, const float* __restrict__ statsR,
    const short* __restrict__ imgWI, const float* __restrict__ uvi,
    const float* __restrict__ ib_l, short* __restrict__ h) {
  __shared__ __align__(16) short panel[32768];
  __shared__ __align__(16) short rep[8192];
  int tid = threadIdx.x, w = tid >> 6, lane = tid & 63;
  int l15 = lane & 15, g4 = lane >> 4;
  int qc = blockIdx.y;
  const short* base = imgWI + (qc >> 1) * 65536;
  int half = qc & 1;
  for (int p = 0; p < 16; ++p)
    gll16(base + (p >> 1) * 8192 + half * 4096 + (p & 1) * 2048 + tid * 8,
          panel + p * 2048 + tid * 8);
  float u0[8], w0[8];
#pragma unroll
  for (int tc = 0; tc < 8; ++tc) {
    int colg = qc * 128 + tc * 16 + l15;
    u0[tc] = uvi[colg];
    w0[tc] = uvi[512 + colg] + ib_l[colg];
  }
  __syncthreads();
  short* myrep = rep + w * 2048;
  for (int t = 0; t < 8; ++t) {
    int seq = blockIdx.x * 8 + t;
    int r0 = seq * 64;
    short8 af[8];
#pragma unroll
    for (int kk = 0; kk < 8; ++kk)
      af[kk] = *(const short8*)(rraw + (size_t)(r0 + w * 16 + l15) * 256 + kk * 32 + g4 * 8);
    float mu[4], rho[4];
#pragma unroll
    for (int r = 0; r < 4; ++r) rowstat<2>(statsR, r0 + w * 16 + g4 * 4 + r, mu[r], rho[r]);
    f32x4 acc[8];
#pragma unroll
    for (int i = 0; i < 8; ++i) acc[i] = f32x4{0.f, 0.f, 0.f, 0.f};
#pragma unroll
    for (int kb = 0; kb < 8; ++kb) {
#pragma unroll
      for (int tc = 0; tc < 8; ++tc) {
        short8 bf = *(const short8*)(panel + kb * 4096 + bswz(tc * 16 + l15, g4));
        acc[tc] = mfma16(af[kb], bf, acc[tc]);
      }
    }
#pragma unroll
    for (int tc = 0; tc < 8; ++tc)
#pragma unroll
      for (int r = 0; r < 4; ++r) {
        float v = rho[r] * (acc[tc][r] - mu[r] * u0[tc]) + w0[tc];
        v = 0.5f * v * (1.f + erff(v * 0.70710678118f));
        myrep[(g4 * 4 + r) * 128 + tc * 16 + l15] = (short)f2b(v);
      }
#pragma unroll
    for (int i = 0; i < 4; ++i) {
      int s = i * 512 + lane * 8;
      int lr = s >> 7, lc = s & 127;
      short8 v = *(const short8*)(myrep + s);
      *(short8*)(h + (size_t)(r0 + w * 16 + lr) * 512 + qc * 128 + lc) = v;
    }
  }
}

// ---- FFN2: y = h@wout + outb + recon(a); store RAW y + stats. grid (200, 4) ----
__global__ __launch_bounds__(256) void ffn2_p(
    const short* __restrict__ h, const short* __restrict__ imgWO,
    const float* __restrict__ outb_l,
    const short* __restrict__ rraw, const float* __restrict__ statsR,
    const float* __restrict__ ag_l, const float* __restrict__ ab_l,
    short* __restrict__ yout, float* __restrict__ statsY) {
  __shared__ __align__(16) short panel[32768];
  __shared__ __align__(16) short rep[4096];  // 1024 shorts per wave
  int tid = threadIdx.x, w = tid >> 6, lane = tid & 63;
  int l15 = lane & 15, g4 = lane >> 4;
  int qc = blockIdx.y;
  for (int p = 0; p < 16; ++p)
    gll16(imgWO + p * 8192 + qc * 2048 + tid * 8, panel + p * 2048 + tid * 8);
  float ob0[4], gr[4], br[4];
#pragma unroll
  for (int tc = 0; tc < 4; ++tc) {
    int colg = qc * 64 + tc * 16 + l15;
    ob0[tc] = outb_l[colg];
    gr[tc] = ag_l[colg];
    br[tc] = ab_l[colg];
  }
  __syncthreads();
  short* myrep = rep + w * 1024;
  for (int t = 0; t < 8; ++t) {
    int seq = blockIdx.x * 8 + t;
    int r0 = seq * 64;
    short8 af[16];
#pragma unroll
    for (int kk = 0; kk < 16; ++kk)
      af[kk] = *(const short8*)(h + (size_t)(r0 + w * 16 + l15) * 512 + kk * 32 + g4 * 8);
    float muR[4], rhoR[4];
#pragma unroll
    for (int r = 0; r < 4; ++r) rowstat<2>(statsR, r0 + w * 16 + g4 * 4 + r, muR[r], rhoR[r]);
    f32x4 acc[4];
#pragma unroll
    for (int i = 0; i < 4; ++i) acc[i] = f32x4{0.f, 0.f, 0.f, 0.f};
#pragma unroll
    for (int kb = 0; kb < 16; ++kb) {
#pragma unroll
      for (int tc = 0; tc < 4; ++tc) {
        short8 bf = *(const short8*)(panel + kb * 2048 + bswz(tc * 16 + l15, g4));
        acc[tc] = mfma16(af[kb], bf, acc[tc]);
      }
    }
#pragma unroll
    for (int i = 0; i < 2; ++i) {
      int s = i * 512 + lane * 8;
      int lr = s >> 6, lc = s & 63;
      short8 v = *(const short8*)(rraw + (size_t)(r0 + w * 16 + lr) * 256 + qc * 64 + lc);
      *(short8*)(myrep + s) = v;
    }
    float s1[4] = {0.f, 0.f, 0.f, 0.f}, s2[4] = {0.f, 0.f, 0.f, 0.f};
#pragma unroll
    for (int tc = 0; tc < 4; ++tc)
#pragma unroll
      for (int r = 0; r < 4; ++r) {
        float raw = b2f((unsigned short)myrep[(g4 * 4 + r) * 64 + tc * 16 + l15]);
        float a = (raw - muR[r]) * rhoR[r] * gr[tc] + br[tc];
        float val = acc[tc][r] + ob0[tc] + a;
        acc[tc][r] = val;
        s1[r] += val; s2[r] += val * val;
      }
#pragma unroll
    for (int r = 0; r < 4; ++r) {
      float a = red16sum(s1[r]), qq = red16sum(s2[r]);
      if (l15 == 0) {
        int row = r0 + w * 16 + g4 * 4 + r;
        statsY[(row * 4 + qc) * 2] = a;
        statsY[(row * 4 + qc) * 2 + 1] = qq;
      }
    }
#pragma unroll
    for (int tc = 0; tc < 4; ++tc)
#pragma unroll
      for (int r = 0; r < 4; ++r)
        myrep[(g4 * 4 + r) * 64 + tc * 16 + l15] = (short)f2b(acc[tc][r]);
#pragma unroll
    for (int i = 0; i < 2; ++i) {
      int s = i * 512 + lane * 8;
      int lr = s >> 6, lc = s & 63;
      short8 v = *(const short8*)(myrep + s);
      *(short8*)(yout + (size_t)(r0 + w * 16 + lr) * 256 + qc * 64 + lc) = v;
    }
  }
}

// ---- pooler: tanh(fold(y_first)@pw' + pb). grid (25, 2) ----
__global__ __launch_bounds__(256) void pool_p(
    const short* __restrict__ yraw, const float* __restrict__ statsY,
    const short* __restrict__ imgWP, const float* __restrict__ uvp,
    const float* __restrict__ pb, float* __restrict__ out) {
  __shared__ __align__(16) short panel[32768];
  int tid = threadIdx.x, w = tid >> 6, lane = tid & 63;
  int l15 = lane & 15, g4 = lane >> 4;
  int half = blockIdx.y;
  for (int p = 0; p < 16; ++p)
    gll16(imgWP + (p >> 1) * 8192 + half * 4096 + (p & 1) * 2048 + tid * 8,
          panel + p * 2048 + tid * 8);
  float u0[8], w0[8];
#pragma unroll
  for (int tc = 0; tc < 8; ++tc) {
    int colg = half * 128 + tc * 16 + l15;
    u0[tc] = uvp[colg];
    w0[tc] = uvp[256 + colg] + pb[colg];
  }
  __syncthreads();
  int s0 = blockIdx.x * 64 + w * 16;
  short8 af[8];
#pragma unroll
  for (int kk = 0; kk < 8; ++kk)
    af[kk] = *(const short8*)(yraw + (size_t)(s0 + l15) * 16384 + kk * 32 + g4 * 8);
  float mu[4], rho[4];
#pragma unroll
  for (int r = 0; r < 4; ++r) rowstat<4>(statsY, (s0 + g4 * 4 + r) * 64, mu[r], rho[r]);
  f32x4 acc[8];
#pragma unroll
  for (int i = 0; i < 8; ++i) acc[i] = f32x4{0.f, 0.f, 0.f, 0.f};
#pragma unroll
  for (int kb = 0; kb < 8; ++kb) {
#pragma unroll
    for (int tc = 0; tc < 8; ++tc) {
      short8 bf = *(const short8*)(panel + kb * 4096 + bswz(tc * 16 + l15, g4));
      acc[tc] = mfma16(af[kb], bf, acc[tc]);
    }
  }
#pragma unroll
  for (int tc = 0; tc < 8; ++tc)
#pragma unroll
    for (int r = 0; r < 4; ++r)
      out[(size_t)(s0 + g4 * 4 + r) * 256 + half * 128 + tc * 16 + l15] =
          tanhf(rho[r] * (acc[tc][r] - mu[r] * u0[tc]) + w0[tc]);
}

extern "C" void kernel_launch(void* const* d_in, const int* in_sizes, int n_in,
                              void* d_out, int out_size, void* d_ws, size_t ws_size,
                              hipStream_t stream) {
  const int* word = (const int*)d_in[0];
  const int* age = (const int*)d_in[1];
  const int* seg = (const int*)d_in[2];
  const int* posi = (const int*)d_in[3];
  const float* mask = (const float*)d_in[4];
  const float* word_emb = (const float*)d_in[6];
  const float* seg_emb = (const float*)d_in[7];
  const float* age_emb = (const float*)d_in[8];
  const float* posi_emb = (const float*)d_in[9];
  const float* emb_g = (const float*)d_in[10];
  const float* emb_b = (const float*)d_in[11];
  const float* qw = (const float*)d_in[12];
  const float* qb = (const float*)d_in[13];
  const float* kw = (const float*)d_in[14];
  const float* kb = (const float*)d_in[15];
  const float* vw = (const float*)d_in[16];
  const float* vb = (const float*)d_in[17];
  const float* ow = (const float*)d_in[18];
  const float* ob = (const float*)d_in[19];
  const float* attn_g = (const float*)d_in[20];
  const float* attn_b = (const float*)d_in[21];
  const float* iw = (const float*)d_in[22];
  const float* ib = (const float*)d_in[23];
  const float* outw = (const float*)d_in[24];
  const float* outb = (const float*)d_in[25];
  const float* out_g = (const float*)d_in[26];
  const float* out_b = (const float*)d_in[27];
  const float* pool_w = (const float*)d_in[28];
  const float* pool_b = (const float*)d_in[29];
  short* ws = (short*)d_ws;

  // shorts: img 1,114,112 | f32 region (uv 5632 + statsR 409600 + statsY 819200)
  //         = 2,468,864 shorts | xy | q | k | vt  (h = q+k, rraw = vt, ctx = q)
  float* fuv = (float*)(ws + 1114112);
  float* stR = fuv + 5632;
  float* stY = stR + 409600;
  short* xy = ws + 1114112 + 2468864;
  short* qbf = xy + 26214400;
  short* kbf = qbf + 26214400;
  short* vtb = kbf + 26214400;
  short* hb = qbf;  // 102400x512 over q+k

  prep_w<<<4352, 256, 0, stream>>>(qw, kw, vw, ow, iw, outw, pool_w, out_g,
                                   attn_g, ws);
  uv_k<<<22, 256, 0, stream>>>(qw, kw, vw, iw, pool_w, emb_g, emb_b, out_g,
                               out_b, attn_g, attn_b, fuv);
  emb_k<<<25600, 256, 0, stream>>>(word, age, seg, posi, word_emb, seg_emb,
                                   age_emb, posi_emb, emb_g, emb_b, xy);
  for (int ly = 0; ly < 2; ++ly) {
    qkv_p<<<dim3(200, 2, 3), 256, 0, stream>>>(
        xy, ly ? stY : nullptr, ws + ly * 65536, fuv + ly * 1536, qb + ly * 256,
        kb + ly * 256, vb + ly * 256, qbf, kbf, vtb);
    attn_k<<<1600, 256, 0, stream>>>(qbf, kbf, vtb, qbf, mask);
    oln_p<<<dim3(200, 2), 256, 0, stream>>>(
        qbf, ws + 393216 + ly * 65536, ob + ly * 256, xy, ly ? stY : nullptr,
        ly ? out_g : nullptr, ly ? out_b : nullptr, vtb, stR);
    ffn1_p<<<dim3(200, 4), 256, 0, stream>>>(vtb, stR, ws + 524288 + ly * 131072,
                                             fuv + 3072 + ly * 1024, ib + ly * 512,
                                             hb);
    ffn2_p<<<dim3(200, 4), 256, 0, stream>>>(hb, ws + 786432 + ly * 131072,
                                             outb + ly * 256, vtb, stR,
                                             attn_g + ly * 256, attn_b + ly * 256,
                                             xy, stY);
  }
  pool_p<<<dim3(25, 2), 256, 0, stream>>>(xy, stY, ws + 1048576, fuv + 5120,
                                          pool_b, (float*)d_out);
}

// Round 10
// 670.238 us; speedup vs baseline: 1.9080x; 1.9080x over previous
//
#include <hip/hip_runtime.h>
#include <math.h>

typedef __attribute__((ext_vector_type(8))) short short8;
typedef __attribute__((ext_vector_type(4))) short short4v;
typedef __attribute__((ext_vector_type(4))) float f32x4;

#define M_TOT 102400  // 1600 seq * 64 tokens

__device__ __forceinline__ unsigned short f2b(float f) {
  unsigned u = __float_as_uint(f);
  return (unsigned short)((u + 0x7fffu + ((u >> 16) & 1u)) >> 16);
}
__device__ __forceinline__ float b2f(unsigned short h) {
  return __uint_as_float(((unsigned)h) << 16);
}
__device__ __forceinline__ f32x4 mfma16(short8 a, short8 b, f32x4 c) {
  return __builtin_amdgcn_mfma_f32_16x16x32_bf16(a, b, c, 0, 0, 0);
}
template <int STRIDE>
__device__ __forceinline__ short8 lds8(const short* buf, int row, int k) {
  int idx = (row * STRIDE + k) ^ ((row & 7) << 3);
  return *(const short8*)(buf + idx);
}
template <int STRIDE>
__device__ __forceinline__ void ldsw(short* buf, int row, int col, unsigned short v) {
  buf[(row * STRIDE + col) ^ ((row & 7) << 3)] = (short)v;
}
__device__ __forceinline__ float red16sum(float v) {
  v += __shfl_xor(v, 1); v += __shfl_xor(v, 2);
  v += __shfl_xor(v, 4); v += __shfl_xor(v, 8);
  return v;
}
__device__ __forceinline__ float red16max(float v) {
  v = fmaxf(v, __shfl_xor(v, 1)); v = fmaxf(v, __shfl_xor(v, 2));
  v = fmaxf(v, __shfl_xor(v, 4)); v = fmaxf(v, __shfl_xor(v, 8));
  return v;
}

// ---- async stage of one 16KB B-chunk: wave w copies bytes [w*4096, +4096) ----
__device__ __forceinline__ void stage16k(const short* __restrict__ g, short* l,
                                         int w, int lane) {
  const char* gb = (const char*)g + w * 4096 + lane * 16;
  char* lb = (char*)l + w * 4096;
#pragma unroll
  for (int c = 0; c < 4; ++c)
    __builtin_amdgcn_global_load_lds(
        (const __attribute__((address_space(1))) unsigned int*)(gb + c * 1024),
        (__attribute__((address_space(3))) unsigned int*)(lb + c * 1024), 16, 0, 0);
}

// ---- staged GEMM core: wave = 16 rows x 256 cols; COUNTED-vmcnt pipeline ----
// Per K-step: s_waitcnt vmcnt(4) (chunk kb landed; kb+1 stays in flight) +
// raw s_barrier — prefetch is never drained (T4). Invariant: chunk kb is older
// than >=4 outstanding VMEM ops, so vmcnt(4) guarantees its completion even if
// the scheduler interleaves unrelated global loads.
template <int KB>
__device__ __forceinline__ void gemm_core(const short* __restrict__ A, int lda,
                                          const short* __restrict__ Wimg,
                                          short* sB, f32x4 acc[16], int r0,
                                          int w, int lane, int l15, int g4) {
  short8 af[KB];
#pragma unroll
  for (int kk = 0; kk < KB; ++kk)
    af[kk] = *(const short8*)(A + (size_t)(r0 + l15) * lda + kk * 32 + g4 * 8);
  stage16k(Wimg, sB, w, lane);
  stage16k(Wimg + 8192, sB + 8192, w, lane);
#pragma unroll
  for (int kb = 0; kb < KB; ++kb) {
    if (kb + 1 < KB) {
      asm volatile("s_waitcnt vmcnt(4)" ::: "memory");
    } else {
      asm volatile("s_waitcnt vmcnt(0)" ::: "memory");
    }
    __builtin_amdgcn_s_barrier();
    __builtin_amdgcn_sched_barrier(0);  // keep ds_reads below the barrier
    const short* cur = sB + (kb & 1) * 8192;
#pragma unroll
    for (int tc = 0; tc < 16; ++tc) {
      int row = tc * 16 + l15;
      short8 bf = *(const short8*)(cur + ((row * 32 + g4 * 8) ^ ((row & 7) << 3)));
      acc[tc] = mfma16(af[kb], bf, acc[tc]);
    }
    if (kb + 2 < KB) {
      __builtin_amdgcn_sched_barrier(0);  // keep ds_reads above the re-stage
      __builtin_amdgcn_s_barrier();
      stage16k(Wimg + (kb + 2) * 8192, sB + (kb & 1) * 8192, w, lane);
    }
  }
}

// ---- LN epilogue: x = LN(acc + bias + x), wave-row-owned (R5 version) ----
__device__ __forceinline__ void ln_epi(f32x4 acc[16], short* x,
                                       const float* __restrict__ bias,
                                       const float* __restrict__ g_,
                                       const float* __restrict__ b_,
                                       int r0, int l15, int g4) {
  float s1[4] = {0.f, 0.f, 0.f, 0.f}, s2[4] = {0.f, 0.f, 0.f, 0.f};
#pragma unroll
  for (int tc = 0; tc < 16; ++tc) {
    int col = tc * 16 + l15;
    float bv = bias[col];
#pragma unroll
    for (int r = 0; r < 4; ++r) {
      float v = acc[tc][r] + bv + b2f((unsigned short)x[(r0 + g4 * 4 + r) * 256 + col]);
      acc[tc][r] = v;
      s1[r] += v; s2[r] += v * v;
    }
  }
  float mean[4], rstd[4];
#pragma unroll
  for (int r = 0; r < 4; ++r) {
    float a = red16sum(s1[r]), q = red16sum(s2[r]);
    mean[r] = a * (1.f / 256.f);
    rstd[r] = rsqrtf(q * (1.f / 256.f) - mean[r] * mean[r] + 1e-12f);
  }
#pragma unroll
  for (int tc = 0; tc < 16; ++tc) {
    int col = tc * 16 + l15;
    float gv = g_[col], bv = b_[col];
#pragma unroll
    for (int r = 0; r < 4; ++r)
      x[(r0 + g4 * 4 + r) * 256 + col] =
          (short)f2b((acc[tc][r] - mean[r]) * rstd[r] * gv + bv);
  }
}

// ---- weight prep: f32 [K][N] -> pre-swizzled bf16 LDS-image chunks ----
// shorts: WQ 0 | WK 131072 | WV 262144 | WO 393216 | WI 524288 | WOUT 786432 | WP 1048576
__global__ void prep_w(const float* __restrict__ qw, const float* __restrict__ kw,
                       const float* __restrict__ vw, const float* __restrict__ ow,
                       const float* __restrict__ iw, const float* __restrict__ outw,
                       const float* __restrict__ pw, short* __restrict__ ws) {
  int t = blockIdx.x * 256 + threadIdx.x;  // 1,114,112 total
  float val; int base, n, k;
  if (t < 524288) {
    int which = t >> 17, r = t & 131071;
    int ly = r >> 16, e = r & 65535;
    n = e >> 8; k = e & 255;
    const float* m = which == 0 ? qw : which == 1 ? kw : which == 2 ? vw : ow;
    val = m[(ly * 256 + k) * 256 + n];
    base = which * 131072 + ly * 65536;
  } else if (t < 786432) {
    int e = t - 524288;
    int ly = e >> 17, f = e & 131071, g2 = f >> 16, e2 = f & 65535;
    n = e2 >> 8; k = e2 & 255;
    val = iw[(ly * 256 + k) * 512 + g2 * 256 + n];
    base = 524288 + ly * 131072 + g2 * 65536;
  } else if (t < 1048576) {
    int e = t - 786432;
    int ly = e >> 17, f = e & 131071;
    n = f >> 9; k = f & 511;
    val = outw[(ly * 512 + k) * 256 + n];
    base = 786432 + ly * 131072;
  } else {
    int e = t - 1048576;
    n = e >> 8; k = e & 255;
    val = pw[k * 256 + n];
    base = 1048576;
  }
  int pos = ((n * 32 + (k & 31)) ^ ((n & 7) << 3));
  ws[base + (k >> 5) * 8192 + pos] = (short)f2b(val);
}

// ---- embedding + LN: wave = one token ----
__global__ __launch_bounds__(256) void emb_k(
    const int* __restrict__ word, const int* __restrict__ age,
    const int* __restrict__ seg, const int* __restrict__ posi,
    const float* __restrict__ we, const float* __restrict__ se,
    const float* __restrict__ ae, const float* __restrict__ pe,
    const float* __restrict__ g, const float* __restrict__ b,
    short* __restrict__ x) {
  int w = threadIdx.x >> 6, lane = threadIdx.x & 63;
  int t = blockIdx.x * 4 + w;
  int wi = word[t], gi = seg[t], ai = age[t], pi = posi[t];
  f32x4 e = ((const f32x4*)(we + wi * 256))[lane];
  f32x4 tv = ((const f32x4*)(se + gi * 256))[lane]; e = e + tv;
  tv = ((const f32x4*)(ae + ai * 256))[lane]; e = e + tv;
  tv = ((const f32x4*)(pe + pi * 256))[lane]; e = e + tv;
  float s1 = e[0] + e[1] + e[2] + e[3];
  float s2 = e[0] * e[0] + e[1] * e[1] + e[2] * e[2] + e[3] * e[3];
#pragma unroll
  for (int m = 1; m < 64; m <<= 1) { s1 += __shfl_xor(s1, m); s2 += __shfl_xor(s2, m); }
  float mean = s1 * (1.f / 256.f);
  float rstd = rsqrtf(s2 * (1.f / 256.f) - mean * mean + 1e-12f);
  f32x4 gv = ((const f32x4*)g)[lane];
  f32x4 bv = ((const f32x4*)b)[lane];
  short4v pk;
#pragma unroll
  for (int j = 0; j < 4; ++j) pk[j] = (short)f2b((e[j] - mean) * rstd * gv[j] + bv[j]);
  *(short4v*)(x + t * 256 + lane * 4) = pk;
}

// ---- QKV: grid (1600, 3); y picks weight/bias/output ----
__global__ __launch_bounds__(256) void qkv3_k(
    const short* __restrict__ x, const short* __restrict__ img,
    const float* __restrict__ qb_, const float* __restrict__ kb_,
    const float* __restrict__ vb_,
    short* __restrict__ q, short* __restrict__ k2, short* __restrict__ vt, int ly) {
  __shared__ __align__(16) short sB[16384];
  int w = threadIdx.x >> 6, lane = threadIdx.x & 63;
  int l15 = lane & 15, g4 = lane >> 4;
  int y = blockIdx.y;
  int r0 = blockIdx.x * 64 + w * 16;
  const short* W = img + y * 131072 + ly * 65536;
  const float* bias = (y == 0 ? qb_ : y == 1 ? kb_ : vb_) + ly * 256;
  f32x4 acc[16];
#pragma unroll
  for (int i = 0; i < 16; ++i) acc[i] = f32x4{0.f, 0.f, 0.f, 0.f};
  gemm_core<8>(x, 256, W, sB, acc, r0, w, lane, l15, g4);
  if (y < 2) {
    short* out = y ? k2 : q;
#pragma unroll
    for (int tc = 0; tc < 16; ++tc) {
      int col = tc * 16 + l15;
      float bv = bias[col];
#pragma unroll
      for (int r = 0; r < 4; ++r)
        out[(r0 + g4 * 4 + r) * 256 + col] = (short)f2b(acc[tc][r] + bv);
    }
  } else {
#pragma unroll
    for (int tc = 0; tc < 16; ++tc) {
      int col = tc * 16 + l15;
      float bv = bias[col];
#pragma unroll
      for (int r = 0; r < 4; ++r) {
        int tok = r0 + g4 * 4 + r;
        vt[(tok >> 6) * 16384 + col * 64 + (tok & 63)] = (short)f2b(acc[tc][r] + bv);
      }
    }
  }
}

// ---- attention: block = seq, wave = head; wave-local softmax; ctx -> global ----
__global__ __launch_bounds__(256) void attn_k(
    const short* __restrict__ q, const short* __restrict__ k,
    const short* __restrict__ vt, short* __restrict__ ctx,
    const float* __restrict__ mask) {
  __shared__ __align__(16) short sP[16384];  // 4 waves x [64][64]
  int w = threadIdx.x >> 6, lane = threadIdx.x & 63;
  int l15 = lane & 15, g4 = lane >> 4;
  int n = blockIdx.x;
  const f32x4 zero4 = {0.f, 0.f, 0.f, 0.f};
  short* sPw = sP + w * 4096;

  float amvr[4];
#pragma unroll
  for (int tc = 0; tc < 4; ++tc)
    amvr[tc] = (1.f - mask[n * 64 + tc * 16 + l15]) * -10000.f;

  const short* qn = q + (size_t)n * 16384;
  const short* kn = k + (size_t)n * 16384;
  const short* vtn = vt + (size_t)n * 16384;

  short8 qa[4][2];
#pragma unroll
  for (int st = 0; st < 4; ++st)
#pragma unroll
    for (int ks = 0; ks < 2; ++ks)
      qa[st][ks] = *(const short8*)(qn + (st * 16 + l15) * 256 + w * 64 + ks * 32 + g4 * 8);
  f32x4 sacc[4][4];
#pragma unroll
  for (int st = 0; st < 4; ++st)
#pragma unroll
    for (int tc = 0; tc < 4; ++tc) sacc[st][tc] = zero4;
#pragma unroll
  for (int ks = 0; ks < 2; ++ks)
#pragma unroll
    for (int tc = 0; tc < 4; ++tc) {
      short8 kf = *(const short8*)(kn + (tc * 16 + l15) * 256 + w * 64 + ks * 32 + g4 * 8);
#pragma unroll
      for (int st = 0; st < 4; ++st) sacc[st][tc] = mfma16(qa[st][ks], kf, sacc[st][tc]);
    }
#pragma unroll
  for (int st = 0; st < 4; ++st)
#pragma unroll
    for (int r = 0; r < 4; ++r) {
      float pv[4];
      float mx = -1e30f;
#pragma unroll
      for (int tc = 0; tc < 4; ++tc) {
        float sv = sacc[st][tc][r] * 0.125f + amvr[tc];
        pv[tc] = sv;
        mx = fmaxf(mx, sv);
      }
      mx = red16max(mx);
      float sm = 0.f;
#pragma unroll
      for (int tc = 0; tc < 4; ++tc) {
        float e = __expf(pv[tc] - mx);
        pv[tc] = e;
        sm += e;
      }
      sm = red16sum(sm);
      float inv = 1.f / sm;
#pragma unroll
      for (int tc = 0; tc < 4; ++tc)
        ldsw<64>(sPw, st * 16 + g4 * 4 + r, tc * 16 + l15, f2b(pv[tc] * inv));
    }
  __syncthreads();  // also orders q-reads (above) vs ctx-writes (below)

  f32x4 cacc[4][4];
#pragma unroll
  for (int st = 0; st < 4; ++st)
#pragma unroll
    for (int tc = 0; tc < 4; ++tc) cacc[st][tc] = zero4;
#pragma unroll
  for (int ks = 0; ks < 2; ++ks) {
    short8 pa[4];
#pragma unroll
    for (int st = 0; st < 4; ++st) pa[st] = lds8<64>(sPw, st * 16 + l15, ks * 32 + g4 * 8);
#pragma unroll
    for (int tc = 0; tc < 4; ++tc) {
      short8 vf = *(const short8*)(vtn + (w * 64 + tc * 16 + l15) * 64 + ks * 32 + g4 * 8);
#pragma unroll
      for (int st = 0; st < 4; ++st) cacc[st][tc] = mfma16(pa[st], vf, cacc[st][tc]);
    }
  }
#pragma unroll
  for (int st = 0; st < 4; ++st)
#pragma unroll
    for (int tc = 0; tc < 4; ++tc)
#pragma unroll
      for (int r = 0; r < 4; ++r)
        ctx[((size_t)n * 64 + st * 16 + g4 * 4 + r) * 256 + w * 64 + tc * 16 + l15] =
            (short)f2b(cacc[st][tc][r]);
}

// ---- O-proj + residual LN: x = LN(ctx@wo + ob + x) ----
__global__ __launch_bounds__(256) void oln_k(
    const short* __restrict__ ctx, const short* __restrict__ img,
    const float* __restrict__ bias, short* __restrict__ x,
    const float* __restrict__ g_, const float* __restrict__ b_) {
  __shared__ __align__(16) short sB[16384];
  int w = threadIdx.x >> 6, lane = threadIdx.x & 63;
  int l15 = lane & 15, g4 = lane >> 4;
  int r0 = blockIdx.x * 64 + w * 16;
  f32x4 acc[16];
#pragma unroll
  for (int i = 0; i < 16; ++i) acc[i] = f32x4{0.f, 0.f, 0.f, 0.f};
  gemm_core<8>(ctx, 256, img, sB, acc, r0, w, lane, l15, g4);
  ln_epi(acc, x, bias, g_, b_, r0, l15, g4);
}

// ---- FFN1: grid (1600, 2); h[:, y*256..] = gelu(x@wi_half + ib) ----
__global__ __launch_bounds__(256) void ffn1_k(
    const short* __restrict__ x, const short* __restrict__ img,
    const float* __restrict__ bias, short* __restrict__ h) {
  __shared__ __align__(16) short sB[16384];
  int w = threadIdx.x >> 6, lane = threadIdx.x & 63;
  int l15 = lane & 15, g4 = lane >> 4;
  int y = blockIdx.y;
  int r0 = blockIdx.x * 64 + w * 16;
  f32x4 acc[16];
#pragma unroll
  for (int i = 0; i < 16; ++i) acc[i] = f32x4{0.f, 0.f, 0.f, 0.f};
  gemm_core<8>(x, 256, img + y * 65536, sB, acc, r0, w, lane, l15, g4);
  const float* bs = bias + y * 256;
#pragma unroll
  for (int tc = 0; tc < 16; ++tc) {
    int col = tc * 16 + l15;
    float bv = bs[col];
#pragma unroll
    for (int r = 0; r < 4; ++r) {
      float v = acc[tc][r] + bv;
      v = 0.5f * v * (1.f + erff(v * 0.70710678118f));
      h[(r0 + g4 * 4 + r) * 512 + y * 256 + col] = (short)f2b(v);
    }
  }
}

// ---- FFN2 + residual LN: x = LN(h@wout + outb + x) ----
__global__ __launch_bounds__(256) void ffn2_k(
    const short* __restrict__ h, const short* __restrict__ img,
    const float* __restrict__ bias, short* __restrict__ x,
    const float* __restrict__ g_, const float* __restrict__ b_) {
  __shared__ __align__(16) short sB[16384];
  int w = threadIdx.x >> 6, lane = threadIdx.x & 63;
  int l15 = lane & 15, g4 = lane >> 4;
  int r0 = blockIdx.x * 64 + w * 16;
  f32x4 acc[16];
#pragma unroll
  for (int i = 0; i < 16; ++i) acc[i] = f32x4{0.f, 0.f, 0.f, 0.f};
  gemm_core<16>(h, 512, img, sB, acc, r0, w, lane, l15, g4);
  ln_epi(acc, x, bias, g_, b_, r0, l15, g4);
}

// ---- pooler: 25 blocks; rows = seqs, A = first token of each seq ----
__global__ __launch_bounds__(256) void pool_k(
    const short* __restrict__ x, const short* __restrict__ img,
    const float* __restrict__ pb, float* __restrict__ out) {
  __shared__ __align__(16) short sB[16384];
  int w = threadIdx.x >> 6, lane = threadIdx.x & 63;
  int l15 = lane & 15, g4 = lane >> 4;
  int r0 = blockIdx.x * 64 + w * 16;  // seq index (25*64 = 1600 exact)
  f32x4 acc[16];
#pragma unroll
  for (int i = 0; i < 16; ++i) acc[i] = f32x4{0.f, 0.f, 0.f, 0.f};
  gemm_core<8>(x, 16384, img, sB, acc, r0, w, lane, l15, g4);
#pragma unroll
  for (int tc = 0; tc < 16; ++tc) {
    int col = tc * 16 + l15;
    float bv = pb[col];
#pragma unroll
    for (int r = 0; r < 4; ++r)
      out[(size_t)(r0 + g4 * 4 + r) * 256 + col] = tanhf(acc[tc][r] + bv);
  }
}

extern "C" void kernel_launch(void* const* d_in, const int* in_sizes, int n_in,
                              void* d_out, int out_size, void* d_ws, size_t ws_size,
                              hipStream_t stream) {
  const int* word = (const int*)d_in[0];
  const int* age = (const int*)d_in[1];
  const int* seg = (const int*)d_in[2];
  const int* posi = (const int*)d_in[3];
  const float* mask = (const float*)d_in[4];
  const float* word_emb = (const float*)d_in[6];
  const float* seg_emb = (const float*)d_in[7];
  const float* age_emb = (const float*)d_in[8];
  const float* posi_emb = (const float*)d_in[9];
  const float* emb_g = (const float*)d_in[10];
  const float* emb_b = (const float*)d_in[11];
  const float* qw = (const float*)d_in[12];
  const float* qb = (const float*)d_in[13];
  const float* kw = (const float*)d_in[14];
  const float* kb = (const float*)d_in[15];
  const float* vw = (const float*)d_in[16];
  const float* vb = (const float*)d_in[17];
  const float* ow = (const float*)d_in[18];
  const float* ob = (const float*)d_in[19];
  const float* attn_g = (const float*)d_in[20];
  const float* attn_b = (const float*)d_in[21];
  const float* iw = (const float*)d_in[22];
  const float* ib = (const float*)d_in[23];
  const float* outw = (const float*)d_in[24];
  const float* outb = (const float*)d_in[25];
  const float* out_g = (const float*)d_in[26];
  const float* out_b = (const float*)d_in[27];
  const float* pool_w = (const float*)d_in[28];
  const float* pool_b = (const float*)d_in[29];
  short* ws = (short*)d_ws;

  // layout (shorts): img 1,114,112 | x 26,214,400 | q | k | vt  (h = q..k span)
  short* xb_ = ws + 1114112;
  short* qbuf = xb_ + 26214400;
  short* kbuf = qbuf + 26214400;
  short* vtbuf = kbuf + 26214400;
  short* hbuf = qbuf;  // 102400x512, overlaps q+k (dead by FFN time)

  prep_w<<<4352, 256, 0, stream>>>(qw, kw, vw, ow, iw, outw, pool_w, ws);
  emb_k<<<25600, 256, 0, stream>>>(word, age, seg, posi, word_emb, seg_emb,
                                   age_emb, posi_emb, emb_g, emb_b, xb_);
  for (int ly = 0; ly < 2; ++ly) {
    qkv3_k<<<dim3(1600, 3), 256, 0, stream>>>(xb_, ws, qb, kb, vb, qbuf, kbuf,
                                              vtbuf, ly);
    attn_k<<<1600, 256, 0, stream>>>(qbuf, kbuf, vtbuf, qbuf, mask);
    oln_k<<<1600, 256, 0, stream>>>(qbuf, ws + 393216 + ly * 65536, ob + ly * 256,
                                    xb_, attn_g + ly * 256, attn_b + ly * 256);
    ffn1_k<<<dim3(1600, 2), 256, 0, stream>>>(xb_, ws + 524288 + ly * 131072,
                                              ib + ly * 512, hbuf);
    ffn2_k<<<1600, 256, 0, stream>>>(hbuf, ws + 786432 + ly * 131072,
                                     outb + ly * 256, xb_, out_g + ly * 256,
                                     out_b + ly * 256);
  }
  pool_k<<<25, 256, 0, stream>>>(xb_, ws + 1048576, pool_b, (float*)d_out);
}